// Round 1
// baseline (439.977 us; speedup 1.0000x reference)
//
#include <hip/hip_runtime.h>

#define N_NODES 65536
#define N_EDGES 1048576
#define F_IN    16
#define H       64
#define N_GRAPHS 32
#define NPG     2048
#define OUT_F   12
#define KPG     (NPG * H)   // 131072 per-graph K for FC

// ---------------------------------------------------------------- CSR build
__global__ void count_kernel(const int* __restrict__ dst, int* __restrict__ counts) {
    int e = blockIdx.x * blockDim.x + threadIdx.x;
    if (e < N_EDGES) atomicAdd(&counts[dst[e]], 1);
}

__global__ __launch_bounds__(1024) void scan_kernel(const int* __restrict__ counts,
                                                    int* __restrict__ rowptr,
                                                    int* __restrict__ cursor,
                                                    float* __restrict__ dinv) {
    __shared__ int sums[1024];
    int t = threadIdx.x;
    // each thread owns 64 contiguous counts; int4 loads for ILP
    const int4* c4 = ((const int4*)counts) + t * 16;
    int s = 0;
#pragma unroll
    for (int i = 0; i < 16; i++) { int4 v = c4[i]; s += v.x + v.y + v.z + v.w; }
    sums[t] = s;
    __syncthreads();
    // Hillis-Steele inclusive scan over 1024 thread-sums
    for (int off = 1; off < 1024; off <<= 1) {
        int v = (t >= off) ? sums[t - off] : 0;
        __syncthreads();
        sums[t] += v;
        __syncthreads();
    }
    int run  = (t == 0) ? 0 : sums[t - 1];
    int base = t * 64;
    for (int i = 0; i < 64; i++) {
        int c = counts[base + i];
        rowptr[base + i] = run;
        cursor[base + i] = run;
        dinv[base + i]   = rsqrtf((float)(c + 1));   // deg = indeg + self-loop
        run += c;
    }
    if (t == 1023) rowptr[N_NODES] = run;
}

__global__ void fill_kernel(const int* __restrict__ src, const int* __restrict__ dst,
                            int* __restrict__ cursor, int* __restrict__ nbr) {
    int e = blockIdx.x * blockDim.x + threadIdx.x;
    if (e < N_EDGES) {
        int d   = dst[e];
        int pos = atomicAdd(&cursor[d], 1);
        nbr[pos] = src[e];
    }
}

// ---------------------------------------------------------------- layer 1
// g1[v] = dinv[v] * x[v]   (N x 16)
__global__ void g1_kernel(const float* __restrict__ x, const float* __restrict__ dinv,
                          float* __restrict__ g1) {
    int i = blockIdx.x * blockDim.x + threadIdx.x;     // float4 index, N*16/4 total
    float4 xv = ((const float4*)x)[i];
    float  dv = dinv[i >> 2];
    float4 r  = make_float4(xv.x * dv, xv.y * dv, xv.z * dv, xv.w * dv);
    ((float4*)g1)[i] = r;
}

// a1[v] = dinv[v] * (g1[v] + sum_{u->v} g1[u])   (16 feats; quarter-wave per edge)
__global__ void agg1_kernel(const float* __restrict__ g1, const int* __restrict__ rowptr,
                            const int* __restrict__ nbr, const float* __restrict__ dinv,
                            float* __restrict__ a1) {
    int v    = (blockIdx.x * blockDim.x + threadIdx.x) >> 6;  // one wave per node
    int lane = threadIdx.x & 63;
    int f    = lane & 15;
    int sub  = lane >> 4;           // 4 edges in flight per wave
    int r0 = rowptr[v], r1 = rowptr[v + 1];
    float acc = 0.f;
    for (int i = r0 + sub; i < r1; i += 4) {
        int u = nbr[i];
        acc += g1[(u << 4) + f];
    }
    acc += __shfl_xor(acc, 16, 64);
    acc += __shfl_xor(acc, 32, 64);
    if (sub == 0) a1[(v << 4) + f] = dinv[v] * (g1[(v << 4) + f] + acc);
}

// g2[v] = dinv[v] * tanh(a1[v] @ W1 + b1)   (N x 64)
__global__ void gemm1_kernel(const float* __restrict__ a1, const float* __restrict__ W1,
                             const float* __restrict__ b1, const float* __restrict__ dinv,
                             float* __restrict__ g2) {
    __shared__ float Ws[F_IN * H];
    __shared__ float bs[H];
    __shared__ float As[4][F_IN];
    int t = threadIdx.x;
    for (int i = t; i < F_IN * H; i += 256) Ws[i] = W1[i];
    if (t < H) bs[t] = b1[t];
    int sub = t >> 6, f = t & 63;
    int v   = blockIdx.x * 4 + sub;
    if (f < F_IN) As[sub][f] = a1[v * F_IN + f];
    __syncthreads();
    float s = bs[f];
#pragma unroll
    for (int k = 0; k < F_IN; k++) s += As[sub][k] * Ws[k * H + f];
    g2[(v << 6) + f] = dinv[v] * tanhf(s);
}

// a2[v] = dinv[v] * (g2[v] + sum_{u->v} g2[u])   (64 feats; wave per node)
__global__ void agg2_kernel(const float* __restrict__ g2, const int* __restrict__ rowptr,
                            const int* __restrict__ nbr, const float* __restrict__ dinv,
                            float* __restrict__ a2) {
    int v    = (blockIdx.x * blockDim.x + threadIdx.x) >> 6;
    int lane = threadIdx.x & 63;
    int r0 = rowptr[v], r1 = rowptr[v + 1];
    float acc = 0.f;
    for (int i = r0; i < r1; i++) {
        int u = nbr[i];
        acc += g2[(u << 6) + lane];
    }
    a2[(v << 6) + lane] = dinv[v] * (acc + g2[(v << 6) + lane]);
}

// h2[v] = tanh(a2[v] @ W2 + b2)   (N x 64)
__global__ void gemm2_kernel(const float* __restrict__ a2, const float* __restrict__ W2,
                             const float* __restrict__ b2, float* __restrict__ h2) {
    __shared__ float Ws[H * H];
    __shared__ float bs[H];
    __shared__ float As[4][H];
    int t = threadIdx.x;
    for (int i = t; i < H * H; i += 256) Ws[i] = W2[i];
    if (t < H) bs[t] = b2[t];
    int sub = t >> 6, f = t & 63;
    int v   = blockIdx.x * 4 + sub;
    As[sub][f] = a2[(v << 6) + f];
    __syncthreads();
    float s = bs[f];
#pragma unroll
    for (int k = 0; k < H; k++) s += As[sub][k] * Ws[k * H + f];
    h2[(v << 6) + f] = tanhf(s);
}

// ---------------------------------------------------------------- FC head
__global__ void init_out_kernel(const float* __restrict__ bfc, float* __restrict__ out) {
    int i = threadIdx.x;          // 384 threads
    out[i] = bfc[i % OUT_F];
}

// out[g][j] += sum over K-chunk of h2_flat[g][k] * Wfc[k][j]
__global__ void fc_kernel(const float* __restrict__ h2, const float* __restrict__ Wfc,
                          float* __restrict__ out) {
    int g = blockIdx.x >> 4;       // 32 graphs
    int c = blockIdx.x & 15;       // 16 chunks of 8192
    int t = threadIdx.x;
    const float* hrow = h2 + g * KPG;
    float acc[OUT_F];
#pragma unroll
    for (int j = 0; j < OUT_F; j++) acc[j] = 0.f;
    int k0 = c * 8192;
    for (int k = k0 + t; k < k0 + 8192; k += 256) {
        float xv = hrow[k];
        const float4* w4 = (const float4*)(Wfc + (size_t)k * OUT_F);
        float4 w0 = w4[0], w1 = w4[1], w2 = w4[2];
        acc[0] += xv * w0.x;  acc[1] += xv * w0.y;  acc[2]  += xv * w0.z;  acc[3]  += xv * w0.w;
        acc[4] += xv * w1.x;  acc[5] += xv * w1.y;  acc[6]  += xv * w1.z;  acc[7]  += xv * w1.w;
        acc[8] += xv * w2.x;  acc[9] += xv * w2.y;  acc[10] += xv * w2.z;  acc[11] += xv * w2.w;
    }
    __shared__ float red[256 * OUT_F];
#pragma unroll
    for (int j = 0; j < OUT_F; j++) red[t * OUT_F + j] = acc[j];
    __syncthreads();
    for (int off = 128; off > 0; off >>= 1) {
        if (t < off) {
#pragma unroll
            for (int j = 0; j < OUT_F; j++)
                red[t * OUT_F + j] += red[(t + off) * OUT_F + j];
        }
        __syncthreads();
    }
    if (t < OUT_F) atomicAdd(&out[g * OUT_F + t], red[t]);
}

// ---------------------------------------------------------------- launcher
extern "C" void kernel_launch(void* const* d_in, const int* in_sizes, int n_in,
                              void* d_out, int out_size, void* d_ws, size_t ws_size,
                              hipStream_t stream) {
    const float* x    = (const float*)d_in[0];
    const int*   edge = (const int*)d_in[1];
    const int*   src  = edge;
    const int*   dst  = edge + N_EDGES;
    // d_in[2] = batch (unused: contiguous equal-size graphs -> reshape)
    const float* W1  = (const float*)d_in[3];
    const float* b1  = (const float*)d_in[4];
    const float* W2  = (const float*)d_in[5];
    const float* b2  = (const float*)d_in[6];
    const float* Wfc = (const float*)d_in[7];
    const float* bfc = (const float*)d_in[8];
    float* out = (float*)d_out;

    char* p = (char*)d_ws;
    auto alloc = [&](size_t n) { char* r = p; p += (n + 255) & ~(size_t)255; return r; };
    int*   counts = (int*)alloc(N_NODES * 4);
    int*   cursor = (int*)alloc(N_NODES * 4);
    int*   rowptr = (int*)alloc((N_NODES + 1) * 4);
    float* dinv   = (float*)alloc(N_NODES * 4);
    int*   nbr    = (int*)alloc(N_EDGES * 4);
    float* g1     = (float*)alloc((size_t)N_NODES * F_IN * 4);
    float* a1     = (float*)alloc((size_t)N_NODES * F_IN * 4);
    float* g2     = (float*)alloc((size_t)N_NODES * H * 4);
    float* a2     = (float*)alloc((size_t)N_NODES * H * 4);
    float* h2     = (float*)alloc((size_t)N_NODES * H * 4);

    hipMemsetAsync(counts, 0, N_NODES * sizeof(int), stream);
    count_kernel<<<N_EDGES / 256, 256, 0, stream>>>(dst, counts);
    scan_kernel<<<1, 1024, 0, stream>>>(counts, rowptr, cursor, dinv);
    fill_kernel<<<N_EDGES / 256, 256, 0, stream>>>(src, dst, cursor, nbr);

    g1_kernel<<<(N_NODES * F_IN / 4) / 256, 256, 0, stream>>>(x, dinv, g1);
    agg1_kernel<<<N_NODES / 4, 256, 0, stream>>>(g1, rowptr, nbr, dinv, a1);
    gemm1_kernel<<<N_NODES / 4, 256, 0, stream>>>(a1, W1, b1, dinv, g2);
    agg2_kernel<<<N_NODES / 4, 256, 0, stream>>>(g2, rowptr, nbr, dinv, a2);
    gemm2_kernel<<<N_NODES / 4, 256, 0, stream>>>(a2, W2, b2, h2);

    init_out_kernel<<<1, N_GRAPHS * OUT_F, 0, stream>>>(bfc, out);
    fc_kernel<<<N_GRAPHS * 16, 256, 0, stream>>>(h2, Wfc, out);
}

// Round 2
// 351.738 us; speedup vs baseline: 1.2509x; 1.2509x over previous
//
#include <hip/hip_runtime.h>

#define N_NODES 65536
#define N_EDGES 1048576
#define F_IN    16
#define H       64
#define N_GRAPHS 32
#define NPG     2048
#define OUT_F   12
#define KPG     (NPG * H)   // 131072 per-graph K for FC

// ---------------------------------------------------------------- CSR build
__global__ void count_kernel(const int* __restrict__ dst, int* __restrict__ counts) {
    int e = blockIdx.x * blockDim.x + threadIdx.x;
    if (e < N_EDGES) atomicAdd(&counts[dst[e]], 1);
}

// A: 256 blocks x 256 thr -> blocksums[256]
__global__ void blocksum_kernel(const int* __restrict__ counts, int* __restrict__ blocksums) {
    int t = threadIdx.x;
    int v = counts[blockIdx.x * 256 + t];
    v += __shfl_down(v, 32, 64); v += __shfl_down(v, 16, 64); v += __shfl_down(v, 8, 64);
    v += __shfl_down(v, 4, 64);  v += __shfl_down(v, 2, 64);  v += __shfl_down(v, 1, 64);
    __shared__ int ws[4];
    if ((t & 63) == 0) ws[t >> 6] = v;
    __syncthreads();
    if (t == 0) blocksums[blockIdx.x] = ws[0] + ws[1] + ws[2] + ws[3];
}

// B: single block of 256 -> exclusive offsets of the 256 block sums
__global__ void scan256_kernel(const int* __restrict__ blocksums, int* __restrict__ blockoffs) {
    int t = threadIdx.x;
    __shared__ int s[256];
    int v = blocksums[t];
    s[t] = v;
    __syncthreads();
    for (int off = 1; off < 256; off <<= 1) {
        int x = (t >= off) ? s[t - off] : 0;
        __syncthreads();
        s[t] += x;
        __syncthreads();
    }
    blockoffs[t] = s[t] - v;   // exclusive
}

// C: 256 blocks x 256 thr -> rowptr/cursor/dinv
__global__ void rowptr_kernel(const int* __restrict__ counts, const int* __restrict__ blockoffs,
                              int* __restrict__ rowptr, int* __restrict__ cursor,
                              float* __restrict__ dinv) {
    int t = threadIdx.x;
    int i = blockIdx.x * 256 + t;
    __shared__ int s[256];
    int c = counts[i];
    s[t] = c;
    __syncthreads();
    for (int off = 1; off < 256; off <<= 1) {
        int x = (t >= off) ? s[t - off] : 0;
        __syncthreads();
        s[t] += x;
        __syncthreads();
    }
    int r = blockoffs[blockIdx.x] + s[t] - c;   // exclusive prefix
    rowptr[i] = r;
    cursor[i] = r;
    dinv[i]   = rsqrtf((float)(c + 1));          // deg = indeg + self-loop
    if (i == 0) rowptr[N_NODES] = N_EDGES;       // total in-edges is known
}

__global__ void fill_kernel(const int* __restrict__ src, const int* __restrict__ dst,
                            int* __restrict__ cursor, int* __restrict__ nbr) {
    int e = blockIdx.x * blockDim.x + threadIdx.x;
    if (e < N_EDGES) {
        int d   = dst[e];
        int pos = atomicAdd(&cursor[d], 1);
        nbr[pos] = src[e];
    }
}

// ---------------------------------------------------------------- layer 1
// g1[v] = dinv[v] * x[v]   (N x 16)
__global__ void g1_kernel(const float* __restrict__ x, const float* __restrict__ dinv,
                          float* __restrict__ g1) {
    int i = blockIdx.x * blockDim.x + threadIdx.x;     // float4 index
    float4 xv = ((const float4*)x)[i];
    float  dv = dinv[i >> 2];
    ((float4*)g1)[i] = make_float4(xv.x * dv, xv.y * dv, xv.z * dv, xv.w * dv);
}

// a1[v] = dinv[v] * (g1[v] + sum_{u->v} g1[u])   (16 feats; 4 sub-streams x unroll4)
__global__ void agg1_kernel(const float* __restrict__ g1, const int* __restrict__ rowptr,
                            const int* __restrict__ nbr, const float* __restrict__ dinv,
                            float* __restrict__ a1) {
    int v    = (blockIdx.x * blockDim.x + threadIdx.x) >> 6;  // one wave per node
    int lane = threadIdx.x & 63;
    int f    = lane & 15;
    int sub  = lane >> 4;           // 4 edge sub-streams per wave
    int r0 = rowptr[v], r1 = rowptr[v + 1];
    float acc = 0.f;
    int i = r0 + sub;
    // 4 edges per sub-stream in flight -> 16 gathers/wave outstanding
    for (; i + 12 < r1; i += 16) {
        int u0 = nbr[i], u1 = nbr[i + 4], u2 = nbr[i + 8], u3 = nbr[i + 12];
        float x0 = g1[(u0 << 4) + f];
        float x1 = g1[(u1 << 4) + f];
        float x2 = g1[(u2 << 4) + f];
        float x3 = g1[(u3 << 4) + f];
        acc += (x0 + x1) + (x2 + x3);
    }
    for (; i < r1; i += 4) acc += g1[(nbr[i] << 4) + f];
    acc += __shfl_xor(acc, 16, 64);
    acc += __shfl_xor(acc, 32, 64);
    if (sub == 0) a1[(v << 4) + f] = dinv[v] * (g1[(v << 4) + f] + acc);
}

// g2[v] = dinv[v] * tanh(a1[v] @ W1 + b1)   (N x 64)
__global__ void gemm1_kernel(const float* __restrict__ a1, const float* __restrict__ W1,
                             const float* __restrict__ b1, const float* __restrict__ dinv,
                             float* __restrict__ g2) {
    __shared__ float Ws[F_IN * H];
    __shared__ float bs[H];
    __shared__ float As[4][F_IN];
    int t = threadIdx.x;
    for (int i = t; i < F_IN * H; i += 256) Ws[i] = W1[i];
    if (t < H) bs[t] = b1[t];
    int sub = t >> 6, f = t & 63;
    int v   = blockIdx.x * 4 + sub;
    if (f < F_IN) As[sub][f] = a1[v * F_IN + f];
    __syncthreads();
    float s = bs[f];
#pragma unroll
    for (int k = 0; k < F_IN; k++) s += As[sub][k] * Ws[k * H + f];
    g2[(v << 6) + f] = dinv[v] * tanhf(s);
}

// a2[v] = dinv[v] * (g2[v] + sum_{u->v} g2[u])   (64 feats; wave per node, unroll 8)
__global__ void agg2_kernel(const float* __restrict__ g2, const int* __restrict__ rowptr,
                            const int* __restrict__ nbr, const float* __restrict__ dinv,
                            float* __restrict__ a2) {
    int v    = (blockIdx.x * blockDim.x + threadIdx.x) >> 6;
    int lane = threadIdx.x & 63;
    int r0 = rowptr[v], r1 = rowptr[v + 1];
    float acc = 0.f;
    int i = r0;
    for (; i + 8 <= r1; i += 8) {
        int u0 = nbr[i],     u1 = nbr[i + 1], u2 = nbr[i + 2], u3 = nbr[i + 3];
        int u4 = nbr[i + 4], u5 = nbr[i + 5], u6 = nbr[i + 6], u7 = nbr[i + 7];
        float x0 = g2[(u0 << 6) + lane];
        float x1 = g2[(u1 << 6) + lane];
        float x2 = g2[(u2 << 6) + lane];
        float x3 = g2[(u3 << 6) + lane];
        float x4 = g2[(u4 << 6) + lane];
        float x5 = g2[(u5 << 6) + lane];
        float x6 = g2[(u6 << 6) + lane];
        float x7 = g2[(u7 << 6) + lane];
        acc += ((x0 + x1) + (x2 + x3)) + ((x4 + x5) + (x6 + x7));
    }
    for (; i < r1; i++) acc += g2[(nbr[i] << 6) + lane];
    a2[(v << 6) + lane] = dinv[v] * (acc + g2[(v << 6) + lane]);
}

// h2[v] = tanh(a2[v] @ W2 + b2)   (N x 64)
__global__ void gemm2_kernel(const float* __restrict__ a2, const float* __restrict__ W2,
                             const float* __restrict__ b2, float* __restrict__ h2) {
    __shared__ float Ws[H * H];
    __shared__ float bs[H];
    __shared__ float As[4][H];
    int t = threadIdx.x;
    for (int i = t; i < H * H; i += 256) Ws[i] = W2[i];
    if (t < H) bs[t] = b2[t];
    int sub = t >> 6, f = t & 63;
    int v   = blockIdx.x * 4 + sub;
    As[sub][f] = a2[(v << 6) + f];
    __syncthreads();
    float s = bs[f];
#pragma unroll
    for (int k = 0; k < H; k++) s += As[sub][k] * Ws[k * H + f];
    h2[(v << 6) + f] = tanhf(s);
}

// ---------------------------------------------------------------- FC head
__global__ void init_out_kernel(const float* __restrict__ bfc, float* __restrict__ out) {
    int i = threadIdx.x;          // 384 threads
    out[i] = bfc[i % OUT_F];
}

// out[g][j] += sum over K-chunk of h2_flat[g][k] * Wfc[k][j]
__global__ void fc_kernel(const float* __restrict__ h2, const float* __restrict__ Wfc,
                          float* __restrict__ out) {
    int g = blockIdx.x >> 4;       // 32 graphs
    int c = blockIdx.x & 15;       // 16 chunks of 8192
    int t = threadIdx.x;
    const float* hrow = h2 + g * KPG;
    float acc[OUT_F];
#pragma unroll
    for (int j = 0; j < OUT_F; j++) acc[j] = 0.f;
    int k0 = c * 8192;
    // each thread: 8 iterations of 4 consecutive k (float4 h load)
    for (int kb = 0; kb < 8; kb++) {
        int k = k0 + (kb * 256 + t) * 4;
        float4 hv = *(const float4*)(hrow + k);
#pragma unroll
        for (int q = 0; q < 4; q++) {
            float xv = (q == 0) ? hv.x : (q == 1) ? hv.y : (q == 2) ? hv.z : hv.w;
            const float4* w4 = (const float4*)(Wfc + (size_t)(k + q) * OUT_F);
            float4 w0 = w4[0], w1 = w4[1], w2 = w4[2];
            acc[0] += xv * w0.x;  acc[1] += xv * w0.y;  acc[2]  += xv * w0.z;  acc[3]  += xv * w0.w;
            acc[4] += xv * w1.x;  acc[5] += xv * w1.y;  acc[6]  += xv * w1.z;  acc[7]  += xv * w1.w;
            acc[8] += xv * w2.x;  acc[9] += xv * w2.y;  acc[10] += xv * w2.z;  acc[11] += xv * w2.w;
        }
    }
    // wave shuffle-reduce, then 4 partials via LDS
#pragma unroll
    for (int j = 0; j < OUT_F; j++) {
        float v = acc[j];
        v += __shfl_down(v, 32, 64); v += __shfl_down(v, 16, 64); v += __shfl_down(v, 8, 64);
        v += __shfl_down(v, 4, 64);  v += __shfl_down(v, 2, 64);  v += __shfl_down(v, 1, 64);
        acc[j] = v;
    }
    __shared__ float red[4][OUT_F];
    int w = t >> 6, ln = t & 63;
    if (ln == 0) {
#pragma unroll
        for (int j = 0; j < OUT_F; j++) red[w][j] = acc[j];
    }
    __syncthreads();
    if (t < OUT_F)
        atomicAdd(&out[g * OUT_F + t], red[0][t] + red[1][t] + red[2][t] + red[3][t]);
}

// ---------------------------------------------------------------- launcher
extern "C" void kernel_launch(void* const* d_in, const int* in_sizes, int n_in,
                              void* d_out, int out_size, void* d_ws, size_t ws_size,
                              hipStream_t stream) {
    const float* x    = (const float*)d_in[0];
    const int*   edge = (const int*)d_in[1];
    const int*   src  = edge;
    const int*   dst  = edge + N_EDGES;
    // d_in[2] = batch (unused: contiguous equal-size graphs -> reshape)
    const float* W1  = (const float*)d_in[3];
    const float* b1  = (const float*)d_in[4];
    const float* W2  = (const float*)d_in[5];
    const float* b2  = (const float*)d_in[6];
    const float* Wfc = (const float*)d_in[7];
    const float* bfc = (const float*)d_in[8];
    float* out = (float*)d_out;

    char* p = (char*)d_ws;
    auto alloc = [&](size_t n) { char* r = p; p += (n + 255) & ~(size_t)255; return r; };
    int*   counts    = (int*)alloc(N_NODES * 4);
    int*   cursor    = (int*)alloc(N_NODES * 4);
    int*   rowptr    = (int*)alloc((N_NODES + 1) * 4);
    float* dinv      = (float*)alloc(N_NODES * 4);
    int*   nbr       = (int*)alloc(N_EDGES * 4);
    int*   blocksums = (int*)alloc(256 * 4);
    int*   blockoffs = (int*)alloc(256 * 4);
    float* g1        = (float*)alloc((size_t)N_NODES * F_IN * 4);
    float* a1        = (float*)alloc((size_t)N_NODES * F_IN * 4);
    float* g2        = (float*)alloc((size_t)N_NODES * H * 4);
    float* a2        = (float*)alloc((size_t)N_NODES * H * 4);
    float* h2        = (float*)alloc((size_t)N_NODES * H * 4);

    hipMemsetAsync(counts, 0, N_NODES * sizeof(int), stream);
    count_kernel<<<N_EDGES / 256, 256, 0, stream>>>(dst, counts);
    blocksum_kernel<<<256, 256, 0, stream>>>(counts, blocksums);
    scan256_kernel<<<1, 256, 0, stream>>>(blocksums, blockoffs);
    rowptr_kernel<<<256, 256, 0, stream>>>(counts, blockoffs, rowptr, cursor, dinv);
    fill_kernel<<<N_EDGES / 256, 256, 0, stream>>>(src, dst, cursor, nbr);

    g1_kernel<<<(N_NODES * F_IN / 4) / 256, 256, 0, stream>>>(x, dinv, g1);
    agg1_kernel<<<N_NODES / 4, 256, 0, stream>>>(g1, rowptr, nbr, dinv, a1);
    gemm1_kernel<<<N_NODES / 4, 256, 0, stream>>>(a1, W1, b1, dinv, g2);
    agg2_kernel<<<N_NODES / 4, 256, 0, stream>>>(g2, rowptr, nbr, dinv, a2);
    gemm2_kernel<<<N_NODES / 4, 256, 0, stream>>>(a2, W2, b2, h2);

    init_out_kernel<<<1, N_GRAPHS * OUT_F, 0, stream>>>(bfc, out);
    fc_kernel<<<N_GRAPHS * 16, 256, 0, stream>>>(h2, Wfc, out);
}

// Round 3
// 272.832 us; speedup vs baseline: 1.6126x; 1.2892x over previous
//
#include <hip/hip_runtime.h>

#define N_NODES 65536
#define N_EDGES 1048576
#define F_IN    16
#define H       64
#define N_GRAPHS 32
#define NPG     2048
#define OUT_F   12
#define KPG     (NPG * H)   // 131072 per-graph K for FC

// ================================================================ CSR build
// Edges pack into uint32: src (16b) | dst (16b) << 16.
// Bucket = dst>>8 (256 buckets of 256 nodes). Two-level LDS counting sort.

// 256 blocks x 256 thr, 4096 edges/block: LDS hist of dst>>8 -> global bucket counts
__global__ __launch_bounds__(256) void bucket_count_kernel(const int* __restrict__ dst,
                                                           int* __restrict__ bucketCnt) {
    __shared__ int h[256];
    int t = threadIdx.x;
    h[t] = 0;
    __syncthreads();
    int base = blockIdx.x * 4096;
#pragma unroll
    for (int i = 0; i < 16; i++) {
        int d = dst[base + i * 256 + t];
        atomicAdd(&h[d >> 8], 1);
    }
    __syncthreads();
    if (h[t]) atomicAdd(&bucketCnt[t], h[t]);
}

// 1 block: exclusive scan of bucket counts -> bucketBase[257], init gCursor
__global__ __launch_bounds__(256) void scan_buckets_kernel(const int* __restrict__ bucketCnt,
                                                           int* __restrict__ bucketBase,
                                                           int* __restrict__ gCursor) {
    int t = threadIdx.x;
    __shared__ int sc[256];
    int c = bucketCnt[t];
    sc[t] = c;
    __syncthreads();
    for (int off = 1; off < 256; off <<= 1) {
        int v = (t >= off) ? sc[t - off] : 0;
        __syncthreads();
        sc[t] += v;
        __syncthreads();
    }
    int excl = sc[t] - c;
    bucketBase[t] = excl;
    gCursor[t]    = excl;
    if (t == 255) bucketBase[256] = N_EDGES;
}

// 256 blocks x 4096 edges: LDS-staged bin by dst>>8, coalesced flush into bucket regions
__global__ __launch_bounds__(256) void binA_kernel(const int* __restrict__ src,
                                                   const int* __restrict__ dst,
                                                   int* __restrict__ gCursor,
                                                   unsigned int* __restrict__ binned) {
    __shared__ int hist[256];
    __shared__ int sc[256];
    __shared__ int bnd[257];      // exclusive staging offsets + sentinel
    __shared__ int lcur[256];
    __shared__ int blkBase[256];
    __shared__ unsigned int staged[4096];
    int t = threadIdx.x;
    hist[t] = 0; lcur[t] = 0;
    __syncthreads();
    int e0 = blockIdx.x * 4096;
    unsigned int rec[16];
#pragma unroll
    for (int i = 0; i < 16; i++) {
        int e = e0 + i * 256 + t;
        unsigned int s = (unsigned int)src[e];
        unsigned int d = (unsigned int)dst[e];
        rec[i] = s | (d << 16);
        atomicAdd(&hist[d >> 8], 1);
    }
    __syncthreads();
    int cnt = hist[t];                                   // my bucket's block-local count
    if (cnt) blkBase[t] = atomicAdd(&gCursor[t], cnt);   // reserve global slot
    sc[t] = cnt;
    __syncthreads();
    for (int off = 1; off < 256; off <<= 1) {
        int v = (t >= off) ? sc[t - off] : 0;
        __syncthreads();
        sc[t] += v;
        __syncthreads();
    }
    bnd[t] = sc[t] - cnt;
    if (t == 255) bnd[256] = 4096;
    __syncthreads();
    // stage records bucket-contiguous in LDS
#pragma unroll
    for (int i = 0; i < 16; i++) {
        int b = rec[i] >> 24;
        int p = bnd[b] + atomicAdd(&lcur[b], 1);
        staged[p] = rec[i];
    }
    __syncthreads();
    // coalesced flush: binary-search the bucket of each staged slot
    for (int i = t; i < 4096; i += 256) {
        int lo = 0;
#pragma unroll
        for (int s = 128; s > 0; s >>= 1)
            if (bnd[lo + s] <= i) lo += s;
        binned[blkBase[lo] + (i - bnd[lo])] = staged[i];
    }
}

// block per bucket: LDS counting sort over 256 nodes -> final nbr (coalesced),
// plus per-node rowptr and dinv as by-products.
__global__ __launch_bounds__(256) void binB_kernel(const unsigned int* __restrict__ binned,
                                                   const int* __restrict__ bucketBase,
                                                   int* __restrict__ rowptr,
                                                   float* __restrict__ dinv,
                                                   int* __restrict__ nbr) {
    __shared__ int hist[256];
    __shared__ int sc[256];
    __shared__ int off[256];
    __shared__ int cur[256];
    __shared__ unsigned short outS[8192];   // src fits in 16 bits; cnt ~4096 +/- ~64
    int b = blockIdx.x, t = threadIdx.x;
    int base = bucketBase[b];
    int cnt  = bucketBase[b + 1] - base;
    hist[t] = 0; cur[t] = 0;
    __syncthreads();
    for (int i = t; i < cnt; i += 256) {
        unsigned int r = binned[base + i];
        atomicAdd(&hist[(r >> 16) & 255], 1);
    }
    __syncthreads();
    int c = hist[t];
    sc[t] = c;
    __syncthreads();
    for (int o = 1; o < 256; o <<= 1) {
        int v = (t >= o) ? sc[t - o] : 0;
        __syncthreads();
        sc[t] += v;
        __syncthreads();
    }
    off[t] = sc[t] - c;
    rowptr[(b << 8) + t] = base + sc[t] - c;
    dinv[(b << 8) + t]   = rsqrtf((float)(c + 1));   // deg = indeg + self-loop
    if (b == 255 && t == 255) rowptr[N_NODES] = N_EDGES;
    __syncthreads();
    for (int i = t; i < cnt; i += 256) {
        unsigned int r = binned[base + i];
        int n = (r >> 16) & 255;
        int p = off[n] + atomicAdd(&cur[n], 1);
        outS[p] = (unsigned short)(r & 0xFFFF);
    }
    __syncthreads();
    for (int i = t; i < cnt; i += 256) nbr[base + i] = (int)outS[i];
}

// ================================================================ layer 1
// g1[v] = dinv[v] * x[v]   (N x 16)
__global__ void g1_kernel(const float* __restrict__ x, const float* __restrict__ dinv,
                          float* __restrict__ g1) {
    int i = blockIdx.x * blockDim.x + threadIdx.x;     // float4 index
    float4 xv = ((const float4*)x)[i];
    float  dv = dinv[i >> 2];
    ((float4*)g1)[i] = make_float4(xv.x * dv, xv.y * dv, xv.z * dv, xv.w * dv);
}

// a1[v] = dinv[v] * (g1[v] + sum_{u->v} g1[u])   (16 feats; 4 sub-streams x unroll4)
__global__ void agg1_kernel(const float* __restrict__ g1, const int* __restrict__ rowptr,
                            const int* __restrict__ nbr, const float* __restrict__ dinv,
                            float* __restrict__ a1) {
    int v    = (blockIdx.x * blockDim.x + threadIdx.x) >> 6;  // one wave per node
    int lane = threadIdx.x & 63;
    int f    = lane & 15;
    int sub  = lane >> 4;           // 4 edge sub-streams per wave
    int r0 = rowptr[v], r1 = rowptr[v + 1];
    float acc = 0.f;
    int i = r0 + sub;
    for (; i + 12 < r1; i += 16) {
        int u0 = nbr[i], u1 = nbr[i + 4], u2 = nbr[i + 8], u3 = nbr[i + 12];
        float x0 = g1[(u0 << 4) + f];
        float x1 = g1[(u1 << 4) + f];
        float x2 = g1[(u2 << 4) + f];
        float x3 = g1[(u3 << 4) + f];
        acc += (x0 + x1) + (x2 + x3);
    }
    for (; i < r1; i += 4) acc += g1[(nbr[i] << 4) + f];
    acc += __shfl_xor(acc, 16, 64);
    acc += __shfl_xor(acc, 32, 64);
    if (sub == 0) a1[(v << 4) + f] = dinv[v] * (g1[(v << 4) + f] + acc);
}

// g2[v] = dinv[v] * tanh(a1[v] @ W1 + b1)   (N x 64)
__global__ void gemm1_kernel(const float* __restrict__ a1, const float* __restrict__ W1,
                             const float* __restrict__ b1, const float* __restrict__ dinv,
                             float* __restrict__ g2) {
    __shared__ float Ws[F_IN * H];
    __shared__ float bs[H];
    __shared__ float As[4][F_IN];
    int t = threadIdx.x;
    for (int i = t; i < F_IN * H; i += 256) Ws[i] = W1[i];
    if (t < H) bs[t] = b1[t];
    int sub = t >> 6, f = t & 63;
    int v   = blockIdx.x * 4 + sub;
    if (f < F_IN) As[sub][f] = a1[v * F_IN + f];
    __syncthreads();
    float s = bs[f];
#pragma unroll
    for (int k = 0; k < F_IN; k++) s += As[sub][k] * Ws[k * H + f];
    g2[(v << 6) + f] = dinv[v] * tanhf(s);
}

// a2[v] = dinv[v] * (g2[v] + sum_{u->v} g2[u])   (64 feats; wave per node, unroll 8)
__global__ void agg2_kernel(const float* __restrict__ g2, const int* __restrict__ rowptr,
                            const int* __restrict__ nbr, const float* __restrict__ dinv,
                            float* __restrict__ a2) {
    int v    = (blockIdx.x * blockDim.x + threadIdx.x) >> 6;
    int lane = threadIdx.x & 63;
    int r0 = rowptr[v], r1 = rowptr[v + 1];
    float acc = 0.f;
    int i = r0;
    for (; i + 8 <= r1; i += 8) {
        int u0 = nbr[i],     u1 = nbr[i + 1], u2 = nbr[i + 2], u3 = nbr[i + 3];
        int u4 = nbr[i + 4], u5 = nbr[i + 5], u6 = nbr[i + 6], u7 = nbr[i + 7];
        float x0 = g2[(u0 << 6) + lane];
        float x1 = g2[(u1 << 6) + lane];
        float x2 = g2[(u2 << 6) + lane];
        float x3 = g2[(u3 << 6) + lane];
        float x4 = g2[(u4 << 6) + lane];
        float x5 = g2[(u5 << 6) + lane];
        float x6 = g2[(u6 << 6) + lane];
        float x7 = g2[(u7 << 6) + lane];
        acc += ((x0 + x1) + (x2 + x3)) + ((x4 + x5) + (x6 + x7));
    }
    for (; i < r1; i++) acc += g2[(nbr[i] << 6) + lane];
    a2[(v << 6) + lane] = dinv[v] * (acc + g2[(v << 6) + lane]);
}

// h2[v] = tanh(a2[v] @ W2 + b2)   (N x 64)
__global__ void gemm2_kernel(const float* __restrict__ a2, const float* __restrict__ W2,
                             const float* __restrict__ b2, float* __restrict__ h2) {
    __shared__ float Ws[H * H];
    __shared__ float bs[H];
    __shared__ float As[4][H];
    int t = threadIdx.x;
    for (int i = t; i < H * H; i += 256) Ws[i] = W2[i];
    if (t < H) bs[t] = b2[t];
    int sub = t >> 6, f = t & 63;
    int v   = blockIdx.x * 4 + sub;
    As[sub][f] = a2[(v << 6) + f];
    __syncthreads();
    float s = bs[f];
#pragma unroll
    for (int k = 0; k < H; k++) s += As[sub][k] * Ws[k * H + f];
    h2[(v << 6) + f] = tanhf(s);
}

// ================================================================ FC head
__global__ void init_out_kernel(const float* __restrict__ bfc, float* __restrict__ out) {
    int i = threadIdx.x;          // 384 threads
    out[i] = bfc[i % OUT_F];
}

__global__ void fc_kernel(const float* __restrict__ h2, const float* __restrict__ Wfc,
                          float* __restrict__ out) {
    int g = blockIdx.x >> 4;       // 32 graphs
    int c = blockIdx.x & 15;       // 16 chunks of 8192
    int t = threadIdx.x;
    const float* hrow = h2 + g * KPG;
    float acc[OUT_F];
#pragma unroll
    for (int j = 0; j < OUT_F; j++) acc[j] = 0.f;
    int k0 = c * 8192;
    for (int kb = 0; kb < 8; kb++) {
        int k = k0 + (kb * 256 + t) * 4;
        float4 hv = *(const float4*)(hrow + k);
#pragma unroll
        for (int q = 0; q < 4; q++) {
            float xv = (q == 0) ? hv.x : (q == 1) ? hv.y : (q == 2) ? hv.z : hv.w;
            const float4* w4 = (const float4*)(Wfc + (size_t)(k + q) * OUT_F);
            float4 w0 = w4[0], w1 = w4[1], w2 = w4[2];
            acc[0] += xv * w0.x;  acc[1] += xv * w0.y;  acc[2]  += xv * w0.z;  acc[3]  += xv * w0.w;
            acc[4] += xv * w1.x;  acc[5] += xv * w1.y;  acc[6]  += xv * w1.z;  acc[7]  += xv * w1.w;
            acc[8] += xv * w2.x;  acc[9] += xv * w2.y;  acc[10] += xv * w2.z;  acc[11] += xv * w2.w;
        }
    }
#pragma unroll
    for (int j = 0; j < OUT_F; j++) {
        float v = acc[j];
        v += __shfl_down(v, 32, 64); v += __shfl_down(v, 16, 64); v += __shfl_down(v, 8, 64);
        v += __shfl_down(v, 4, 64);  v += __shfl_down(v, 2, 64);  v += __shfl_down(v, 1, 64);
        acc[j] = v;
    }
    __shared__ float red[4][OUT_F];
    int w = t >> 6, ln = t & 63;
    if (ln == 0) {
#pragma unroll
        for (int j = 0; j < OUT_F; j++) red[w][j] = acc[j];
    }
    __syncthreads();
    if (t < OUT_F)
        atomicAdd(&out[g * OUT_F + t], red[0][t] + red[1][t] + red[2][t] + red[3][t]);
}

// ================================================================ launcher
extern "C" void kernel_launch(void* const* d_in, const int* in_sizes, int n_in,
                              void* d_out, int out_size, void* d_ws, size_t ws_size,
                              hipStream_t stream) {
    const float* x    = (const float*)d_in[0];
    const int*   edge = (const int*)d_in[1];
    const int*   src  = edge;
    const int*   dst  = edge + N_EDGES;
    // d_in[2] = batch (unused: contiguous equal-size graphs -> reshape)
    const float* W1  = (const float*)d_in[3];
    const float* b1  = (const float*)d_in[4];
    const float* W2  = (const float*)d_in[5];
    const float* b2  = (const float*)d_in[6];
    const float* Wfc = (const float*)d_in[7];
    const float* bfc = (const float*)d_in[8];
    float* out = (float*)d_out;

    char* p = (char*)d_ws;
    auto alloc = [&](size_t n) { char* r = p; p += (n + 255) & ~(size_t)255; return r; };
    int*   bucketCnt  = (int*)alloc(256 * 4);
    int*   bucketBase = (int*)alloc(257 * 4);
    int*   gCursor    = (int*)alloc(256 * 4);
    int*   rowptr     = (int*)alloc((N_NODES + 1) * 4);
    float* dinv       = (float*)alloc(N_NODES * 4);
    int*   nbr        = (int*)alloc(N_EDGES * 4);
    float* g1         = (float*)alloc((size_t)N_NODES * F_IN * 4);   // also 'binned' (4 MB, dead before g1 written)
    float* a1         = (float*)alloc((size_t)N_NODES * F_IN * 4);
    float* g2         = (float*)alloc((size_t)N_NODES * H * 4);      // also 'h2' (g2 dead before h2 written)
    float* a2         = (float*)alloc((size_t)N_NODES * H * 4);
    unsigned int* binned = (unsigned int*)g1;
    float* h2         = g2;

    hipMemsetAsync(bucketCnt, 0, 256 * sizeof(int), stream);
    bucket_count_kernel<<<256, 256, 0, stream>>>(dst, bucketCnt);
    scan_buckets_kernel<<<1, 256, 0, stream>>>(bucketCnt, bucketBase, gCursor);
    binA_kernel<<<256, 256, 0, stream>>>(src, dst, gCursor, binned);
    binB_kernel<<<256, 256, 0, stream>>>(binned, bucketBase, rowptr, dinv, nbr);

    g1_kernel<<<(N_NODES * F_IN / 4) / 256, 256, 0, stream>>>(x, dinv, g1);
    agg1_kernel<<<N_NODES / 4, 256, 0, stream>>>(g1, rowptr, nbr, dinv, a1);
    gemm1_kernel<<<N_NODES / 4, 256, 0, stream>>>(a1, W1, b1, dinv, g2);
    agg2_kernel<<<N_NODES / 4, 256, 0, stream>>>(g2, rowptr, nbr, dinv, a2);
    gemm2_kernel<<<N_NODES / 4, 256, 0, stream>>>(a2, W2, b2, h2);

    init_out_kernel<<<1, N_GRAPHS * OUT_F, 0, stream>>>(bfc, out);
    fc_kernel<<<N_GRAPHS * 16, 256, 0, stream>>>(h2, Wfc, out);
}

// Round 4
// 271.951 us; speedup vs baseline: 1.6179x; 1.0032x over previous
//
#include <hip/hip_runtime.h>
#include <hip/hip_fp16.h>

#define N_NODES 65536
#define N_EDGES 1048576
#define F_IN    16
#define H       64
#define N_GRAPHS 32
#define NPG     2048
#define OUT_F   12
#define KPG     (NPG * H)   // 131072 per-graph K for FC

// ================================================================ CSR build
// Edges pack into uint32: src (16b) | dst (16b) << 16.
// Bucket = dst>>8 (256 buckets of 256 nodes). Two-level LDS counting sort.

__global__ __launch_bounds__(256) void bucket_count_kernel(const int* __restrict__ dst,
                                                           int* __restrict__ bucketCnt) {
    __shared__ int h[256];
    int t = threadIdx.x;
    h[t] = 0;
    __syncthreads();
    int base = blockIdx.x * 4096;
#pragma unroll
    for (int i = 0; i < 16; i++) {
        int d = dst[base + i * 256 + t];
        atomicAdd(&h[d >> 8], 1);
    }
    __syncthreads();
    if (h[t]) atomicAdd(&bucketCnt[t], h[t]);
}

// 1 block: scan bucket counts -> bucketBase[257], init gCursor; also bias-init out
__global__ __launch_bounds__(256) void scan_buckets_kernel(const int* __restrict__ bucketCnt,
                                                           int* __restrict__ bucketBase,
                                                           int* __restrict__ gCursor,
                                                           const float* __restrict__ bfc,
                                                           float* __restrict__ out) {
    int t = threadIdx.x;
    __shared__ int sc[256];
    int c = bucketCnt[t];
    sc[t] = c;
    __syncthreads();
    for (int off = 1; off < 256; off <<= 1) {
        int v = (t >= off) ? sc[t - off] : 0;
        __syncthreads();
        sc[t] += v;
        __syncthreads();
    }
    int excl = sc[t] - c;
    bucketBase[t] = excl;
    gCursor[t]    = excl;
    if (t == 255) bucketBase[256] = N_EDGES;
    for (int i = t; i < N_GRAPHS * OUT_F; i += 256) out[i] = bfc[i % OUT_F];
}

// 256 blocks x 4096 edges: LDS-staged bin by dst>>8, coalesced flush into bucket regions
__global__ __launch_bounds__(256) void binA_kernel(const int* __restrict__ src,
                                                   const int* __restrict__ dst,
                                                   int* __restrict__ gCursor,
                                                   unsigned int* __restrict__ binned) {
    __shared__ int hist[256];
    __shared__ int sc[256];
    __shared__ int bnd[257];
    __shared__ int lcur[256];
    __shared__ int blkBase[256];
    __shared__ unsigned int staged[4096];
    int t = threadIdx.x;
    hist[t] = 0; lcur[t] = 0;
    __syncthreads();
    int e0 = blockIdx.x * 4096;
    unsigned int rec[16];
#pragma unroll
    for (int i = 0; i < 16; i++) {
        int e = e0 + i * 256 + t;
        unsigned int s = (unsigned int)src[e];
        unsigned int d = (unsigned int)dst[e];
        rec[i] = s | (d << 16);
        atomicAdd(&hist[d >> 8], 1);
    }
    __syncthreads();
    int cnt = hist[t];
    if (cnt) blkBase[t] = atomicAdd(&gCursor[t], cnt);
    sc[t] = cnt;
    __syncthreads();
    for (int off = 1; off < 256; off <<= 1) {
        int v = (t >= off) ? sc[t - off] : 0;
        __syncthreads();
        sc[t] += v;
        __syncthreads();
    }
    bnd[t] = sc[t] - cnt;
    if (t == 255) bnd[256] = 4096;
    __syncthreads();
#pragma unroll
    for (int i = 0; i < 16; i++) {
        int b = rec[i] >> 24;
        int p = bnd[b] + atomicAdd(&lcur[b], 1);
        staged[p] = rec[i];
    }
    __syncthreads();
    for (int i = t; i < 4096; i += 256) {
        int lo = 0;
#pragma unroll
        for (int s = 128; s > 0; s >>= 1)
            if (bnd[lo + s] <= i) lo += s;
        binned[blkBase[lo] + (i - bnd[lo])] = staged[i];
    }
}

// block per bucket: LDS counting sort over 256 nodes -> nbr (ushort, coalesced),
// rowptr and dinv as by-products.
__global__ __launch_bounds__(256) void binB_kernel(const unsigned int* __restrict__ binned,
                                                   const int* __restrict__ bucketBase,
                                                   int* __restrict__ rowptr,
                                                   float* __restrict__ dinv,
                                                   unsigned short* __restrict__ nbr) {
    __shared__ int hist[256];
    __shared__ int sc[256];
    __shared__ int off[256];
    __shared__ int cur[256];
    __shared__ unsigned short outS[8192];
    int b = blockIdx.x, t = threadIdx.x;
    int base = bucketBase[b];
    int cnt  = bucketBase[b + 1] - base;
    hist[t] = 0; cur[t] = 0;
    __syncthreads();
    for (int i = t; i < cnt; i += 256) {
        unsigned int r = binned[base + i];
        atomicAdd(&hist[(r >> 16) & 255], 1);
    }
    __syncthreads();
    int c = hist[t];
    sc[t] = c;
    __syncthreads();
    for (int o = 1; o < 256; o <<= 1) {
        int v = (t >= o) ? sc[t - o] : 0;
        __syncthreads();
        sc[t] += v;
        __syncthreads();
    }
    off[t] = sc[t] - c;
    rowptr[(b << 8) + t] = base + sc[t] - c;
    dinv[(b << 8) + t]   = rsqrtf((float)(c + 1));
    if (b == 255 && t == 255) rowptr[N_NODES] = N_EDGES;
    __syncthreads();
    for (int i = t; i < cnt; i += 256) {
        unsigned int r = binned[base + i];
        int n = (r >> 16) & 255;
        int p = off[n] + atomicAdd(&cur[n], 1);
        outS[p] = (unsigned short)(r & 0xFFFF);
    }
    __syncthreads();
    for (int i = t; i < cnt; i += 256) nbr[base + i] = outS[i];
}

// ================================================================ layer 1
__global__ void g1_kernel(const float* __restrict__ x, const float* __restrict__ dinv,
                          float* __restrict__ g1) {
    int i = blockIdx.x * blockDim.x + threadIdx.x;
    float4 xv = ((const float4*)x)[i];
    float  dv = dinv[i >> 2];
    ((float4*)g1)[i] = make_float4(xv.x * dv, xv.y * dv, xv.z * dv, xv.w * dv);
}

__global__ void agg1_kernel(const float* __restrict__ g1, const int* __restrict__ rowptr,
                            const unsigned short* __restrict__ nbr,
                            const float* __restrict__ dinv, float* __restrict__ a1) {
    int v    = (blockIdx.x * blockDim.x + threadIdx.x) >> 6;
    int lane = threadIdx.x & 63;
    int f    = lane & 15;
    int sub  = lane >> 4;
    int r0 = rowptr[v], r1 = rowptr[v + 1];
    float acc = 0.f;
    int i = r0 + sub;
    for (; i + 12 < r1; i += 16) {
        int u0 = nbr[i], u1 = nbr[i + 4], u2 = nbr[i + 8], u3 = nbr[i + 12];
        float x0 = g1[(u0 << 4) + f];
        float x1 = g1[(u1 << 4) + f];
        float x2 = g1[(u2 << 4) + f];
        float x3 = g1[(u3 << 4) + f];
        acc += (x0 + x1) + (x2 + x3);
    }
    for (; i < r1; i += 4) acc += g1[((int)nbr[i] << 4) + f];
    acc += __shfl_xor(acc, 16, 64);
    acc += __shfl_xor(acc, 32, 64);
    if (sub == 0) a1[(v << 4) + f] = dinv[v] * (g1[(v << 4) + f] + acc);
}

// g2h[v] = fp16( dinv[v] * tanh(a1[v] @ W1 + b1) )   (N x 64, half)
__global__ void gemm1_kernel(const float* __restrict__ a1, const float* __restrict__ W1,
                             const float* __restrict__ b1, const float* __restrict__ dinv,
                             __half* __restrict__ g2h) {
    __shared__ float Ws[F_IN * H];
    __shared__ float bs[H];
    __shared__ float As[4][F_IN];
    int t = threadIdx.x;
    for (int i = t; i < F_IN * H; i += 256) Ws[i] = W1[i];
    if (t < H) bs[t] = b1[t];
    int sub = t >> 6, f = t & 63;
    int v   = blockIdx.x * 4 + sub;
    if (f < F_IN) As[sub][f] = a1[v * F_IN + f];
    __syncthreads();
    float s = bs[f];
#pragma unroll
    for (int k = 0; k < F_IN; k++) s += As[sub][k] * Ws[k * H + f];
    g2h[(v << 6) + f] = __float2half(dinv[v] * tanhf(s));
}

// a2 = dinv*(g2h[self] + gather-sum)   -- feature-sliced: 2 slices x 32 feats (one
// 64B line per node per slice; 4 MB slice footprint = per-XCD L2). slice from blockIdx
// so slice-0 blocks drain (mostly) before slice-1 starts.
__global__ __launch_bounds__(256) void agg2_kernel(const __half2* __restrict__ g2h,
                                                   const int* __restrict__ rowptr,
                                                   const unsigned short* __restrict__ nbr,
                                                   const float* __restrict__ dinv,
                                                   float2* __restrict__ a2) {
    int bid   = blockIdx.x;
    int slice = bid >> 14;                                // 16384 blocks per slice
    int v     = ((bid & 16383) << 2) + (threadIdx.x >> 6);
    int lane  = threadIdx.x & 63;
    int f2    = lane & 15;
    int sub   = lane >> 4;
    int col   = (slice << 4) + f2;                        // half2 column in [0,32)
    int r0 = rowptr[v], r1 = rowptr[v + 1];
    float ax = 0.f, ay = 0.f;
    int i = r0 + sub;
    for (; i + 12 < r1; i += 16) {
        int u0 = nbr[i], u1 = nbr[i + 4], u2 = nbr[i + 8], u3 = nbr[i + 12];
        float2 x0 = __half22float2(g2h[(u0 << 5) + col]);
        float2 x1 = __half22float2(g2h[(u1 << 5) + col]);
        float2 x2 = __half22float2(g2h[(u2 << 5) + col]);
        float2 x3 = __half22float2(g2h[(u3 << 5) + col]);
        ax += (x0.x + x1.x) + (x2.x + x3.x);
        ay += (x0.y + x1.y) + (x2.y + x3.y);
    }
    for (; i < r1; i += 4) {
        float2 xv = __half22float2(g2h[((int)nbr[i] << 5) + col]);
        ax += xv.x; ay += xv.y;
    }
    ax += __shfl_xor(ax, 16, 64); ax += __shfl_xor(ax, 32, 64);
    ay += __shfl_xor(ay, 16, 64); ay += __shfl_xor(ay, 32, 64);
    if (sub == 0) {
        float2 sv = __half22float2(g2h[(v << 5) + col]);
        float dv = dinv[v];
        a2[(v << 5) + col] = make_float2(dv * (ax + sv.x), dv * (ay + sv.y));
    }
}

// h2[v] = tanh(a2[v] @ W2 + b2)   (N x 64, fp32)
__global__ void gemm2_kernel(const float* __restrict__ a2, const float* __restrict__ W2,
                             const float* __restrict__ b2, float* __restrict__ h2) {
    __shared__ float Ws[H * H];
    __shared__ float bs[H];
    __shared__ float As[4][H];
    int t = threadIdx.x;
    for (int i = t; i < H * H; i += 256) Ws[i] = W2[i];
    if (t < H) bs[t] = b2[t];
    int sub = t >> 6, f = t & 63;
    int v   = blockIdx.x * 4 + sub;
    As[sub][f] = a2[(v << 6) + f];
    __syncthreads();
    float s = bs[f];
#pragma unroll
    for (int k = 0; k < H; k++) s += As[sub][k] * Ws[k * H + f];
    h2[(v << 6) + f] = tanhf(s);
}

// ================================================================ FC head
// grid: 128 kchunks (1024 k) x 4 graph-groups (8 graphs) = 512 blocks x 256 thr.
// Wfc read once per group (24 MB total), h once (16 MB).
__global__ __launch_bounds__(256) void fc_kernel(const float* __restrict__ h2,
                                                 const float* __restrict__ Wfc,
                                                 float* __restrict__ out) {
    int kc = blockIdx.x & 127;
    int gg = blockIdx.x >> 7;
    int t  = threadIdx.x;
    float acc[8][12];
#pragma unroll
    for (int g = 0; g < 8; g++)
#pragma unroll
        for (int j = 0; j < OUT_F; j++) acc[g][j] = 0.f;
    const float* hbase = h2 + (size_t)gg * 8 * KPG;
#pragma unroll
    for (int i = 0; i < 4; i++) {
        int k = (kc << 10) + (i << 8) + t;
        const float4* w4 = (const float4*)(Wfc + (size_t)k * OUT_F);
        float4 w0 = w4[0], w1 = w4[1], w2 = w4[2];
        float hv[8];
#pragma unroll
        for (int g = 0; g < 8; g++) hv[g] = hbase[(size_t)g * KPG + k];
#pragma unroll
        for (int g = 0; g < 8; g++) {
            acc[g][0] += hv[g] * w0.x;  acc[g][1] += hv[g] * w0.y;
            acc[g][2] += hv[g] * w0.z;  acc[g][3] += hv[g] * w0.w;
            acc[g][4] += hv[g] * w1.x;  acc[g][5] += hv[g] * w1.y;
            acc[g][6] += hv[g] * w1.z;  acc[g][7] += hv[g] * w1.w;
            acc[g][8] += hv[g] * w2.x;  acc[g][9] += hv[g] * w2.y;
            acc[g][10] += hv[g] * w2.z; acc[g][11] += hv[g] * w2.w;
        }
    }
#pragma unroll
    for (int g = 0; g < 8; g++)
#pragma unroll
        for (int j = 0; j < OUT_F; j++) {
            float v = acc[g][j];
            v += __shfl_xor(v, 1, 64);  v += __shfl_xor(v, 2, 64);
            v += __shfl_xor(v, 4, 64);  v += __shfl_xor(v, 8, 64);
            v += __shfl_xor(v, 16, 64); v += __shfl_xor(v, 32, 64);
            acc[g][j] = v;
        }
    __shared__ float red[4][96];
    int w = t >> 6;
    if ((t & 63) == 0) {
#pragma unroll
        for (int g = 0; g < 8; g++)
#pragma unroll
            for (int j = 0; j < OUT_F; j++) red[w][g * OUT_F + j] = acc[g][j];
    }
    __syncthreads();
    if (t < 96)
        atomicAdd(&out[gg * 96 + t], red[0][t] + red[1][t] + red[2][t] + red[3][t]);
}

// ================================================================ launcher
extern "C" void kernel_launch(void* const* d_in, const int* in_sizes, int n_in,
                              void* d_out, int out_size, void* d_ws, size_t ws_size,
                              hipStream_t stream) {
    const float* x    = (const float*)d_in[0];
    const int*   edge = (const int*)d_in[1];
    const int*   src  = edge;
    const int*   dst  = edge + N_EDGES;
    const float* W1  = (const float*)d_in[3];
    const float* b1  = (const float*)d_in[4];
    const float* W2  = (const float*)d_in[5];
    const float* b2  = (const float*)d_in[6];
    const float* Wfc = (const float*)d_in[7];
    const float* bfc = (const float*)d_in[8];
    float* out = (float*)d_out;

    char* p = (char*)d_ws;
    auto alloc = [&](size_t n) { char* r = p; p += (n + 255) & ~(size_t)255; return r; };
    int*   bucketCnt  = (int*)alloc(256 * 4);
    int*   bucketBase = (int*)alloc(257 * 4);
    int*   gCursor    = (int*)alloc(256 * 4);
    int*   rowptr     = (int*)alloc((N_NODES + 1) * 4);
    float* dinv       = (float*)alloc(N_NODES * 4);
    unsigned short* nbr = (unsigned short*)alloc(N_EDGES * 2);
    float* g1         = (float*)alloc((size_t)N_NODES * F_IN * 4);  // aliases 'binned'
    float* a1         = (float*)alloc((size_t)N_NODES * F_IN * 4);
    __half* g2h       = (__half*)alloc((size_t)N_NODES * H * 2);
    float* a2         = (float*)alloc((size_t)N_NODES * H * 4);
    float* h2         = (float*)alloc((size_t)N_NODES * H * 4);
    unsigned int* binned = (unsigned int*)g1;

    hipMemsetAsync(bucketCnt, 0, 256 * sizeof(int), stream);
    bucket_count_kernel<<<256, 256, 0, stream>>>(dst, bucketCnt);
    scan_buckets_kernel<<<1, 256, 0, stream>>>(bucketCnt, bucketBase, gCursor, bfc, out);
    binA_kernel<<<256, 256, 0, stream>>>(src, dst, gCursor, binned);
    binB_kernel<<<256, 256, 0, stream>>>(binned, bucketBase, rowptr, dinv, nbr);

    g1_kernel<<<(N_NODES * F_IN / 4) / 256, 256, 0, stream>>>(x, dinv, g1);
    agg1_kernel<<<N_NODES / 4, 256, 0, stream>>>(g1, rowptr, nbr, dinv, a1);
    gemm1_kernel<<<N_NODES / 4, 256, 0, stream>>>(a1, W1, b1, dinv, g2h);
    agg2_kernel<<<2 * (N_NODES / 4), 256, 0, stream>>>((const __half2*)g2h, rowptr, nbr, dinv,
                                                       (float2*)a2);
    gemm2_kernel<<<N_NODES / 4, 256, 0, stream>>>(a2, W2, b2, h2);

    fc_kernel<<<512, 256, 0, stream>>>(h2, Wfc, out);
}

// Round 5
// 238.327 us; speedup vs baseline: 1.8461x; 1.1411x over previous
//
#include <hip/hip_runtime.h>
#include <hip/hip_fp16.h>

#define N_NODES 65536
#define N_EDGES 1048576
#define F_IN    16
#define H       64
#define N_GRAPHS 32
#define NPG     2048
#define OUT_F   12
#define KPG     (NPG * H)   // 131072 per-graph K for FC

// ================================================================ CSR build
// Edges pack into uint32: src (16b) | dst (16b) << 16.
// Bucket = dst>>8 (256 buckets of 256 nodes). Two-level LDS counting sort.

__global__ __launch_bounds__(256) void bucket_count_kernel(const int* __restrict__ dst,
                                                           int* __restrict__ bucketCnt) {
    __shared__ int h[256];
    int t = threadIdx.x;
    h[t] = 0;
    __syncthreads();
    int base = blockIdx.x * 4096;
#pragma unroll
    for (int i = 0; i < 16; i++) {
        int d = dst[base + i * 256 + t];
        atomicAdd(&h[d >> 8], 1);
    }
    __syncthreads();
    if (h[t]) atomicAdd(&bucketCnt[t], h[t]);
}

// 1 block: scan bucket counts -> bucketBase[257], init gCursor; also bias-init out
__global__ __launch_bounds__(256) void scan_buckets_kernel(const int* __restrict__ bucketCnt,
                                                           int* __restrict__ bucketBase,
                                                           int* __restrict__ gCursor,
                                                           const float* __restrict__ bfc,
                                                           float* __restrict__ out) {
    int t = threadIdx.x;
    __shared__ int sc[256];
    int c = bucketCnt[t];
    sc[t] = c;
    __syncthreads();
    for (int off = 1; off < 256; off <<= 1) {
        int v = (t >= off) ? sc[t - off] : 0;
        __syncthreads();
        sc[t] += v;
        __syncthreads();
    }
    int excl = sc[t] - c;
    bucketBase[t] = excl;
    gCursor[t]    = excl;
    if (t == 255) bucketBase[256] = N_EDGES;
    for (int i = t; i < N_GRAPHS * OUT_F; i += 256) out[i] = bfc[i % OUT_F];
}

// 256 blocks x 4096 edges: LDS-staged bin by dst>>8, coalesced flush into bucket regions
__global__ __launch_bounds__(256) void binA_kernel(const int* __restrict__ src,
                                                   const int* __restrict__ dst,
                                                   int* __restrict__ gCursor,
                                                   unsigned int* __restrict__ binned) {
    __shared__ int hist[256];
    __shared__ int sc[256];
    __shared__ int bnd[257];
    __shared__ int lcur[256];
    __shared__ int blkBase[256];
    __shared__ unsigned int staged[4096];
    int t = threadIdx.x;
    hist[t] = 0; lcur[t] = 0;
    __syncthreads();
    int e0 = blockIdx.x * 4096;
    unsigned int rec[16];
#pragma unroll
    for (int i = 0; i < 16; i++) {
        int e = e0 + i * 256 + t;
        unsigned int s = (unsigned int)src[e];
        unsigned int d = (unsigned int)dst[e];
        rec[i] = s | (d << 16);
        atomicAdd(&hist[d >> 8], 1);
    }
    __syncthreads();
    int cnt = hist[t];
    if (cnt) blkBase[t] = atomicAdd(&gCursor[t], cnt);
    sc[t] = cnt;
    __syncthreads();
    for (int off = 1; off < 256; off <<= 1) {
        int v = (t >= off) ? sc[t - off] : 0;
        __syncthreads();
        sc[t] += v;
        __syncthreads();
    }
    bnd[t] = sc[t] - cnt;
    if (t == 255) bnd[256] = 4096;
    __syncthreads();
#pragma unroll
    for (int i = 0; i < 16; i++) {
        int b = rec[i] >> 24;
        int p = bnd[b] + atomicAdd(&lcur[b], 1);
        staged[p] = rec[i];
    }
    __syncthreads();
    for (int i = t; i < 4096; i += 256) {
        int lo = 0;
#pragma unroll
        for (int s = 128; s > 0; s >>= 1)
            if (bnd[lo + s] <= i) lo += s;
        binned[blkBase[lo] + (i - bnd[lo])] = staged[i];
    }
}

// block per bucket: LDS counting sort over 256 nodes -> nbr (ushort, coalesced),
// rowptr and dinv as by-products.
__global__ __launch_bounds__(256) void binB_kernel(const unsigned int* __restrict__ binned,
                                                   const int* __restrict__ bucketBase,
                                                   int* __restrict__ rowptr,
                                                   float* __restrict__ dinv,
                                                   unsigned short* __restrict__ nbr) {
    __shared__ int hist[256];
    __shared__ int sc[256];
    __shared__ int off[256];
    __shared__ int cur[256];
    __shared__ unsigned short outS[8192];
    int b = blockIdx.x, t = threadIdx.x;
    int base = bucketBase[b];
    int cnt  = bucketBase[b + 1] - base;
    hist[t] = 0; cur[t] = 0;
    __syncthreads();
    for (int i = t; i < cnt; i += 256) {
        unsigned int r = binned[base + i];
        atomicAdd(&hist[(r >> 16) & 255], 1);
    }
    __syncthreads();
    int c = hist[t];
    sc[t] = c;
    __syncthreads();
    for (int o = 1; o < 256; o <<= 1) {
        int v = (t >= o) ? sc[t - o] : 0;
        __syncthreads();
        sc[t] += v;
        __syncthreads();
    }
    off[t] = sc[t] - c;
    rowptr[(b << 8) + t] = base + sc[t] - c;
    dinv[(b << 8) + t]   = rsqrtf((float)(c + 1));
    if (b == 255 && t == 255) rowptr[N_NODES] = N_EDGES;
    __syncthreads();
    for (int i = t; i < cnt; i += 256) {
        unsigned int r = binned[base + i];
        int n = (r >> 16) & 255;
        int p = off[n] + atomicAdd(&cur[n], 1);
        outS[p] = (unsigned short)(r & 0xFFFF);
    }
    __syncthreads();
    for (int i = t; i < cnt; i += 256) nbr[base + i] = outS[i];
}

// ================================================================ layer 1
// g1h[v] = fp16( dinv[v] * x[v] )   (N x 16, half -> 2 MB, L2-resident)
__global__ void g1_kernel(const float* __restrict__ x, const float* __restrict__ dinv,
                          __half2* __restrict__ g1h2) {
    int i = blockIdx.x * blockDim.x + threadIdx.x;   // float4 index
    float4 xv = ((const float4*)x)[i];
    float  dv = dinv[i >> 2];
    g1h2[2 * i]     = __floats2half2_rn(xv.x * dv, xv.y * dv);
    g1h2[2 * i + 1] = __floats2half2_rn(xv.z * dv, xv.w * dv);
}

// a1[v] = dinv[v]*(g1[v] + sum g1[u]); wave per node, lane = (sub<3 bits>, f2<3 bits>):
// 8 edges per round, row = 8 half2 (32B). nbr loaded once coalesced + shfl broadcast.
__global__ __launch_bounds__(256) void agg1_kernel(const __half2* __restrict__ g1h2,
                                                   const int* __restrict__ rowptr,
                                                   const unsigned short* __restrict__ nbr,
                                                   const float* __restrict__ dinv,
                                                   float2* __restrict__ a1) {
    int v    = (blockIdx.x * blockDim.x + threadIdx.x) >> 6;
    int lane = threadIdx.x & 63;
    int f2   = lane & 7;
    int sub  = lane >> 3;
    int r0 = rowptr[v], r1 = rowptr[v + 1];
    float ax = 0.f, ay = 0.f;
    for (int base = r0; base < r1; base += 64) {
        int er = min(64, r1 - base);
        int nb = (int)nbr[base + lane];     // coalesced; lanes >= er hold unused data
        int j = 0;
        for (; j + 16 <= er; j += 16) {     // 2 rounds of 8 edges
            int u0 = __shfl(nb, j + sub, 64);
            int u1 = __shfl(nb, j + 8 + sub, 64);
            float2 x0 = __half22float2(g1h2[(u0 << 3) + f2]);
            float2 x1 = __half22float2(g1h2[(u1 << 3) + f2]);
            ax += x0.x + x1.x;
            ay += x0.y + x1.y;
        }
        for (; j < er; j += 8) {
            int idx = j + sub;
            int u = __shfl(nb, idx < er ? idx : 0, 64);
            float2 xv = __half22float2(g1h2[(u << 3) + f2]);
            if (idx < er) { ax += xv.x; ay += xv.y; }
        }
    }
    ax += __shfl_xor(ax, 8, 64);  ax += __shfl_xor(ax, 16, 64);  ax += __shfl_xor(ax, 32, 64);
    ay += __shfl_xor(ay, 8, 64);  ay += __shfl_xor(ay, 16, 64);  ay += __shfl_xor(ay, 32, 64);
    if (sub == 0) {
        float2 sv = __half22float2(g1h2[(v << 3) + f2]);
        float dv = dinv[v];
        a1[(v << 3) + f2] = make_float2(dv * (ax + sv.x), dv * (ay + sv.y));
    }
}

// g2h[v] = fp16( dinv[v] * tanh(a1[v] @ W1 + b1) )   (N x 64, half)
__global__ void gemm1_kernel(const float* __restrict__ a1, const float* __restrict__ W1,
                             const float* __restrict__ b1, const float* __restrict__ dinv,
                             __half* __restrict__ g2h) {
    __shared__ float Ws[F_IN * H];
    __shared__ float bs[H];
    __shared__ float As[4][F_IN];
    int t = threadIdx.x;
    for (int i = t; i < F_IN * H; i += 256) Ws[i] = W1[i];
    if (t < H) bs[t] = b1[t];
    int sub = t >> 6, f = t & 63;
    int v   = blockIdx.x * 4 + sub;
    if (f < F_IN) As[sub][f] = a1[v * F_IN + f];
    __syncthreads();
    float s = bs[f];
#pragma unroll
    for (int k = 0; k < F_IN; k++) s += As[sub][k] * Ws[k * H + f];
    g2h[(v << 6) + f] = __float2half(dinv[v] * tanhf(s));
}

// a2[v] = dinv[v]*(g2[v] + sum g2[u]); wave per node, lane = (sub<1 bit>, f2<5 bits>):
// 2 edges per round (each 32-lane half covers the full 128B fp16 row).
__global__ __launch_bounds__(256) void agg2_kernel(const __half2* __restrict__ g2h2,
                                                   const int* __restrict__ rowptr,
                                                   const unsigned short* __restrict__ nbr,
                                                   const float* __restrict__ dinv,
                                                   float2* __restrict__ a2) {
    int v    = (blockIdx.x * blockDim.x + threadIdx.x) >> 6;
    int lane = threadIdx.x & 63;
    int f2   = lane & 31;
    int sub  = lane >> 5;
    int r0 = rowptr[v], r1 = rowptr[v + 1];
    float ax = 0.f, ay = 0.f;
    for (int base = r0; base < r1; base += 64) {
        int er = min(64, r1 - base);
        int nb = (int)nbr[base + lane];
        int j = 0;
        for (; j + 8 <= er; j += 8) {       // 4 rounds of 2 edges: 4 gathers in flight
            int u0 = __shfl(nb, j + sub, 64);
            int u1 = __shfl(nb, j + 2 + sub, 64);
            int u2 = __shfl(nb, j + 4 + sub, 64);
            int u3 = __shfl(nb, j + 6 + sub, 64);
            float2 x0 = __half22float2(g2h2[(u0 << 5) + f2]);
            float2 x1 = __half22float2(g2h2[(u1 << 5) + f2]);
            float2 x2 = __half22float2(g2h2[(u2 << 5) + f2]);
            float2 x3 = __half22float2(g2h2[(u3 << 5) + f2]);
            ax += (x0.x + x1.x) + (x2.x + x3.x);
            ay += (x0.y + x1.y) + (x2.y + x3.y);
        }
        for (; j < er; j += 2) {
            int idx = j + sub;
            int u = __shfl(nb, idx < er ? idx : 0, 64);
            float2 xv = __half22float2(g2h2[(u << 5) + f2]);
            if (idx < er) { ax += xv.x; ay += xv.y; }
        }
    }
    ax += __shfl_xor(ax, 32, 64);
    ay += __shfl_xor(ay, 32, 64);
    if (sub == 0) {
        float2 sv = __half22float2(g2h2[(v << 5) + f2]);
        float dv = dinv[v];
        a2[(v << 5) + f2] = make_float2(dv * (ax + sv.x), dv * (ay + sv.y));
    }
}

// h2[v] = tanh(a2[v] @ W2 + b2)   (N x 64, fp32)
__global__ void gemm2_kernel(const float* __restrict__ a2, const float* __restrict__ W2,
                             const float* __restrict__ b2, float* __restrict__ h2) {
    __shared__ float Ws[H * H];
    __shared__ float bs[H];
    __shared__ float As[4][H];
    int t = threadIdx.x;
    for (int i = t; i < H * H; i += 256) Ws[i] = W2[i];
    if (t < H) bs[t] = b2[t];
    int sub = t >> 6, f = t & 63;
    int v   = blockIdx.x * 4 + sub;
    As[sub][f] = a2[(v << 6) + f];
    __syncthreads();
    float s = bs[f];
#pragma unroll
    for (int k = 0; k < H; k++) s += As[sub][k] * Ws[k * H + f];
    h2[(v << 6) + f] = tanhf(s);
}

// ================================================================ FC head
// grid: 128 kchunks (1024 k) x 4 graph-groups (8 graphs) = 512 blocks x 256 thr.
__global__ __launch_bounds__(256) void fc_kernel(const float* __restrict__ h2,
                                                 const float* __restrict__ Wfc,
                                                 float* __restrict__ out) {
    int kc = blockIdx.x & 127;
    int gg = blockIdx.x >> 7;
    int t  = threadIdx.x;
    float acc[8][12];
#pragma unroll
    for (int g = 0; g < 8; g++)
#pragma unroll
        for (int j = 0; j < OUT_F; j++) acc[g][j] = 0.f;
    const float* hbase = h2 + (size_t)gg * 8 * KPG;
#pragma unroll
    for (int i = 0; i < 4; i++) {
        int k = (kc << 10) + (i << 8) + t;
        const float4* w4 = (const float4*)(Wfc + (size_t)k * OUT_F);
        float4 w0 = w4[0], w1 = w4[1], w2 = w4[2];
        float hv[8];
#pragma unroll
        for (int g = 0; g < 8; g++) hv[g] = hbase[(size_t)g * KPG + k];
#pragma unroll
        for (int g = 0; g < 8; g++) {
            acc[g][0] += hv[g] * w0.x;  acc[g][1] += hv[g] * w0.y;
            acc[g][2] += hv[g] * w0.z;  acc[g][3] += hv[g] * w0.w;
            acc[g][4] += hv[g] * w1.x;  acc[g][5] += hv[g] * w1.y;
            acc[g][6] += hv[g] * w1.z;  acc[g][7] += hv[g] * w1.w;
            acc[g][8] += hv[g] * w2.x;  acc[g][9] += hv[g] * w2.y;
            acc[g][10] += hv[g] * w2.z; acc[g][11] += hv[g] * w2.w;
        }
    }
#pragma unroll
    for (int g = 0; g < 8; g++)
#pragma unroll
        for (int j = 0; j < OUT_F; j++) {
            float v = acc[g][j];
            v += __shfl_xor(v, 1, 64);  v += __shfl_xor(v, 2, 64);
            v += __shfl_xor(v, 4, 64);  v += __shfl_xor(v, 8, 64);
            v += __shfl_xor(v, 16, 64); v += __shfl_xor(v, 32, 64);
            acc[g][j] = v;
        }
    __shared__ float red[4][96];
    int w = t >> 6;
    if ((t & 63) == 0) {
#pragma unroll
        for (int g = 0; g < 8; g++)
#pragma unroll
            for (int j = 0; j < OUT_F; j++) red[w][g * OUT_F + j] = acc[g][j];
    }
    __syncthreads();
    if (t < 96)
        atomicAdd(&out[gg * 96 + t], red[0][t] + red[1][t] + red[2][t] + red[3][t]);
}

// ================================================================ launcher
extern "C" void kernel_launch(void* const* d_in, const int* in_sizes, int n_in,
                              void* d_out, int out_size, void* d_ws, size_t ws_size,
                              hipStream_t stream) {
    const float* x    = (const float*)d_in[0];
    const int*   edge = (const int*)d_in[1];
    const int*   src  = edge;
    const int*   dst  = edge + N_EDGES;
    const float* W1  = (const float*)d_in[3];
    const float* b1  = (const float*)d_in[4];
    const float* W2  = (const float*)d_in[5];
    const float* b2  = (const float*)d_in[6];
    const float* Wfc = (const float*)d_in[7];
    const float* bfc = (const float*)d_in[8];
    float* out = (float*)d_out;

    char* p = (char*)d_ws;
    auto alloc = [&](size_t n) { char* r = p; p += (n + 255) & ~(size_t)255; return r; };
    int*   bucketCnt  = (int*)alloc(256 * 4);
    int*   bucketBase = (int*)alloc(257 * 4);
    int*   gCursor    = (int*)alloc(256 * 4);
    int*   rowptr     = (int*)alloc((N_NODES + 1) * 4);
    float* dinv       = (float*)alloc(N_NODES * 4);
    unsigned short* nbr = (unsigned short*)alloc(N_EDGES * 2 + 256); // pad: agg reads up to +63
    __half* g1h       = (__half*)alloc((size_t)N_NODES * F_IN * 2);
    float* a1         = (float*)alloc((size_t)N_NODES * F_IN * 4);
    __half* g2h       = (__half*)alloc((size_t)N_NODES * H * 2);
    float* a2         = (float*)alloc((size_t)N_NODES * H * 4);
    float* h2         = (float*)alloc((size_t)N_NODES * H * 4);
    unsigned int* binned = (unsigned int*)alloc((size_t)N_EDGES * 4);

    hipMemsetAsync(bucketCnt, 0, 256 * sizeof(int), stream);
    bucket_count_kernel<<<256, 256, 0, stream>>>(dst, bucketCnt);
    scan_buckets_kernel<<<1, 256, 0, stream>>>(bucketCnt, bucketBase, gCursor, bfc, out);
    binA_kernel<<<256, 256, 0, stream>>>(src, dst, gCursor, binned);
    binB_kernel<<<256, 256, 0, stream>>>(binned, bucketBase, rowptr, dinv, nbr);

    g1_kernel<<<(N_NODES * F_IN / 4) / 256, 256, 0, stream>>>(x, dinv, (__half2*)g1h);
    agg1_kernel<<<N_NODES / 4, 256, 0, stream>>>((const __half2*)g1h, rowptr, nbr, dinv,
                                                 (float2*)a1);
    gemm1_kernel<<<N_NODES / 4, 256, 0, stream>>>(a1, W1, b1, dinv, g2h);
    agg2_kernel<<<N_NODES / 4, 256, 0, stream>>>((const __half2*)g2h, rowptr, nbr, dinv,
                                                 (float2*)a2);
    gemm2_kernel<<<N_NODES / 4, 256, 0, stream>>>(a2, W2, b2, h2);

    fc_kernel<<<512, 256, 0, stream>>>(h2, Wfc, out);
}